// Round 4
// baseline (37.853 us; speedup 1.0000x reference)
//
#include <hip/hip_runtime.h>

#define B_   16
#define T_   10
#define D_   256
#define MI_  32
#define MO_  16
#define RES_ 200
#define OG_    4                        // o-groups in kernel A
#define OPG    (MO_ / OG_)              // 4 o per A block
#define CS_STRIDE (2 * MO_ * D_)        // 8192 floats per bt
#define CS_BYTES ((size_t)B_ * T_ * CS_STRIDE * sizeof(float))  // 5.24 MB

// B geometry: 100 mirror pair-slots p=0..99; block = 64 hp x 4 ss,
// each ss owns 5 slots; 20 slots per block -> 5 chunks per bt.
#define SLOTS_PER_SS   5
#define SLOTS_PER_BLK  20
#define CHUNKS_PER_BT  5                // 100 / 20

// ---------- Kernel A: complex contraction -> C,S planes in ws --------------
// (unchanged from round 3)
__global__ __launch_bounds__(256) void spectral_cs(
    const float* __restrict__ v,
    const float* __restrict__ w_real,
    const float* __restrict__ w_imag,
    float* __restrict__ ws)
{
    const int blk = blockIdx.x;
    const int bt  = blk >> 2;
    const int og  = blk & 3;
    const int t   = bt % T_;
    const int d   = threadIdx.x;

    __shared__ float s_w[OPG][2][MI_];   // [o_local][re/im][m], 1 KB

    const float* wrt = w_real + (size_t)(t * MO_ + og * OPG) * MI_;
    const float* wit = w_imag + (size_t)(t * MO_ + og * OPG) * MI_;
    {
        int ol = threadIdx.x >> 6;
        int ri = (threadIdx.x >> 5) & 1;
        int m  = threadIdx.x & 31;
        s_w[ol][ri][m] = ri ? wit[ol * MI_ + m] : wrt[ol * MI_ + m];
    }
    __syncthreads();

    float rr[MI_], ii[MI_];
    const float4* vp = reinterpret_cast<const float4*>(
        v + (size_t)(bt * D_ + d) * (2 * MI_));
    #pragma unroll
    for (int j = 0; j < MI_ / 4; ++j) {
        float4 q = vp[j];
        rr[4*j+0]=q.x; rr[4*j+1]=q.y; rr[4*j+2]=q.z; rr[4*j+3]=q.w;
    }
    #pragma unroll
    for (int j = 0; j < MI_ / 4; ++j) {
        float4 q = vp[MI_/4 + j];
        ii[4*j+0]=q.x; ii[4*j+1]=q.y; ii[4*j+2]=q.z; ii[4*j+3]=q.w;
    }

    float* wsp = ws + (size_t)bt * CS_STRIDE;
    #pragma unroll
    for (int ol = 0; ol < OPG; ++ol) {
        float c = 0.f, s = 0.f;
        #pragma unroll
        for (int mq = 0; mq < MI_ / 4; ++mq) {
            float4 a4 = *reinterpret_cast<const float4*>(&s_w[ol][0][mq*4]);
            float4 b4 = *reinterpret_cast<const float4*>(&s_w[ol][1][mq*4]);
            c = fmaf(rr[mq*4+0], a4.x, c); c = fmaf(-ii[mq*4+0], b4.x, c);
            s = fmaf(rr[mq*4+0], b4.x, s); s = fmaf( ii[mq*4+0], a4.x, s);
            c = fmaf(rr[mq*4+1], a4.y, c); c = fmaf(-ii[mq*4+1], b4.y, c);
            s = fmaf(rr[mq*4+1], b4.y, s); s = fmaf( ii[mq*4+1], a4.y, s);
            c = fmaf(rr[mq*4+2], a4.z, c); c = fmaf(-ii[mq*4+2], b4.z, c);
            s = fmaf(rr[mq*4+2], b4.z, s); s = fmaf( ii[mq*4+2], a4.z, s);
            c = fmaf(rr[mq*4+3], a4.w, c); c = fmaf(-ii[mq*4+3], b4.w, c);
            s = fmaf(rr[mq*4+3], b4.w, s); s = fmaf( ii[mq*4+3], a4.w, s);
        }
        const int o = og * OPG + ol;
        wsp[o * D_ + d]         = c;
        wsp[(MO_ + o) * D_ + d] = s;
    }
}

// ---------- Kernel B: mirror-symmetric inverse transform -------------------
// grid 800 = bt(160) x chunk(5); block 256 = hp(64, 4 h each) x ss(4).
// a = sum_o C*cos, b = sum_o S*sin  ->  out[p] = a-b, out[200-p] = a+b.
__global__ __launch_bounds__(256) void spectral_ift(
    const float* __restrict__ ws,
    float* __restrict__ out)
{
    const int blk   = blockIdx.x;
    const int bt    = blk / CHUNKS_PER_BT;
    const int chunk = blk % CHUNKS_PER_BT;
    const int hp    = threadIdx.x & 63;
    const int ss    = threadIdx.x >> 6;
    const int h0    = hp * 4;

    // [local slot][o] -> (cos, sin) pairs
    __shared__ float s_trig[SLOTS_PER_BLK][2 * MO_];

    for (int idx = threadIdx.x; idx < SLOTS_PER_BLK * MO_; idx += 256) {
        int sl = idx >> 4;
        int o  = idx & 15;
        int p  = chunk * SLOTS_PER_BLK + sl;
        int k  = (o * p) % RES_;
        float ang = 6.28318530717958647692f * ((float)k * (1.0f / (float)RES_));
        float sv, cv;
        __sincosf(ang, &sv, &cv);
        s_trig[sl][2 * o]     = cv;
        s_trig[sl][2 * o + 1] = sv;
    }
    __syncthreads();

    const bool flag0 = (chunk == 0) && (ss == 0);  // wave-uniform

    float a[SLOTS_PER_SS][4] = {};
    float bb[SLOTS_PER_SS][4] = {};
    float c100[4] = {};

    const float* wsp = ws + (size_t)bt * CS_STRIDE;
    #pragma unroll
    for (int o = 0; o < MO_; ++o) {
        float4 C4 = *reinterpret_cast<const float4*>(&wsp[o * D_ + h0]);
        float4 S4 = *reinterpret_cast<const float4*>(&wsp[(MO_ + o) * D_ + h0]);
        #pragma unroll
        for (int i = 0; i < SLOTS_PER_SS; ++i) {
            float2 t = *reinterpret_cast<const float2*>(
                &s_trig[ss * SLOTS_PER_SS + i][2 * o]);  // broadcast ds_read_b64
            a[i][0]  = fmaf(C4.x, t.x, a[i][0]);
            a[i][1]  = fmaf(C4.y, t.x, a[i][1]);
            a[i][2]  = fmaf(C4.z, t.x, a[i][2]);
            a[i][3]  = fmaf(C4.w, t.x, a[i][3]);
            bb[i][0] = fmaf(S4.x, t.y, bb[i][0]);
            bb[i][1] = fmaf(S4.y, t.y, bb[i][1]);
            bb[i][2] = fmaf(S4.z, t.y, bb[i][2]);
            bb[i][3] = fmaf(S4.w, t.y, bb[i][3]);
        }
        if (flag0) {    // x=100 row: cos = (-1)^o, sin = 0
            float sgn = (o & 1) ? -1.0f : 1.0f;
            c100[0] = fmaf(C4.x, sgn, c100[0]);
            c100[1] = fmaf(C4.y, sgn, c100[1]);
            c100[2] = fmaf(C4.z, sgn, c100[2]);
            c100[3] = fmaf(C4.w, sgn, c100[3]);
        }
    }

    float* obase = out + (size_t)bt * RES_ * D_ + h0;
    #pragma unroll
    for (int i = 0; i < SLOTS_PER_SS; ++i) {
        const int p  = chunk * SLOTS_PER_BLK + ss * SLOTS_PER_SS + i;
        const int x2 = (RES_ - p) % RES_;   // mirror row (p=0 -> 0, benign dup)
        float4 lo, hi;
        lo.x = a[i][0] - bb[i][0]; hi.x = a[i][0] + bb[i][0];
        lo.y = a[i][1] - bb[i][1]; hi.y = a[i][1] + bb[i][1];
        lo.z = a[i][2] - bb[i][2]; hi.z = a[i][2] + bb[i][2];
        lo.w = a[i][3] - bb[i][3]; hi.w = a[i][3] + bb[i][3];
        *reinterpret_cast<float4*>(&obase[(size_t)p  * D_]) = lo;
        *reinterpret_cast<float4*>(&obase[(size_t)x2 * D_]) = hi;
    }
    if (flag0) {
        float4 r; r.x = c100[0]; r.y = c100[1]; r.z = c100[2]; r.w = c100[3];
        *reinterpret_cast<float4*>(&obase[(size_t)100 * D_]) = r;
    }
}

// ---------- Fallback (ws too small): fused kernel --------------------------
__global__ __launch_bounds__(256) void spectral_fused(
    const float* __restrict__ v,
    const float* __restrict__ w_real,
    const float* __restrict__ w_imag,
    float* __restrict__ out)
{
    const int bt = blockIdx.x;
    const int t  = bt % T_;
    const int d  = threadIdx.x;

    __shared__ float s_wr[MO_ * MI_];
    __shared__ float s_wi[MO_ * MI_];
    __shared__ float s_trig[RES_][2 * MO_];

    const float* wrt = w_real + t * MO_ * MI_;
    const float* wit = w_imag + t * MO_ * MI_;
    for (int idx = threadIdx.x; idx < MO_ * MI_; idx += 256) {
        s_wr[idx] = wrt[idx];
        s_wi[idx] = wit[idx];
    }
    for (int idx = threadIdx.x; idx < RES_ * MO_; idx += 256) {
        int x = idx >> 4;
        int o = idx & 15;
        int k = (o * x) % RES_;
        float ang = 6.28318530717958647692f * ((float)k * (1.0f / (float)RES_));
        float sv, cv;
        __sincosf(ang, &sv, &cv);
        s_trig[x][o]       = cv;
        s_trig[x][o + MO_] = -sv;
    }
    __syncthreads();

    float rr[MI_], ii[MI_];
    const float4* vp = reinterpret_cast<const float4*>(
        v + (size_t)(bt * D_ + d) * (2 * MI_));
    #pragma unroll
    for (int j = 0; j < MI_ / 4; ++j) {
        float4 q = vp[j];
        rr[4*j+0]=q.x; rr[4*j+1]=q.y; rr[4*j+2]=q.z; rr[4*j+3]=q.w;
    }
    #pragma unroll
    for (int j = 0; j < MI_ / 4; ++j) {
        float4 q = vp[MI_/4 + j];
        ii[4*j+0]=q.x; ii[4*j+1]=q.y; ii[4*j+2]=q.z; ii[4*j+3]=q.w;
    }

    float C[MO_], S[MO_];
    #pragma unroll
    for (int o = 0; o < MO_; ++o) {
        float c = 0.f, s = 0.f;
        #pragma unroll
        for (int m = 0; m < MI_; ++m) {
            float aw = s_wr[o * MI_ + m];
            float bw = s_wi[o * MI_ + m];
            c = fmaf(rr[m], aw, c);
            c = fmaf(-ii[m], bw, c);
            s = fmaf(rr[m], bw, s);
            s = fmaf(ii[m], aw, s);
        }
        C[o] = c;
        S[o] = s;
    }

    float* op = out + (size_t)bt * RES_ * D_ + d;
    for (int x = 0; x < RES_; ++x) {
        float acc = 0.f;
        #pragma unroll
        for (int o = 0; o < MO_; ++o) {
            acc = fmaf(C[o], s_trig[x][o],       acc);
            acc = fmaf(S[o], s_trig[x][o + MO_], acc);
        }
        op[(size_t)x * D_] = acc;
    }
}

extern "C" void kernel_launch(void* const* d_in, const int* in_sizes, int n_in,
                              void* d_out, int out_size, void* d_ws, size_t ws_size,
                              hipStream_t stream) {
    const float* v  = (const float*)d_in[0];
    const float* wr = (const float*)d_in[1];
    const float* wi = (const float*)d_in[2];
    float* out = (float*)d_out;

    if (ws_size >= CS_BYTES) {
        float* ws = (float*)d_ws;
        spectral_cs <<<B_ * T_ * OG_,           256, 0, stream>>>(v, wr, wi, ws);
        spectral_ift<<<B_ * T_ * CHUNKS_PER_BT, 256, 0, stream>>>(ws, out);
    } else {
        spectral_fused<<<B_ * T_, 256, 0, stream>>>(v, wr, wi, out);
    }
}

// Round 5
// 34.729 us; speedup vs baseline: 1.0900x; 1.0900x over previous
//
#include <hip/hip_runtime.h>

#define B_   16
#define T_   10
#define D_   256
#define MI_  32
#define MO_  16
#define RES_ 200
#define TWO_PI 6.28318530717958647692f

// Single fused kernel. grid 640 = bt(160) x hq(4); block 256 threads.
// Phase 1: threads = (h_l 64) x (og 4): C,S contraction -> LDS.
// Phase 2: threads = (hp 16, 4h each) x (ss 16): mirror IFT, trig via
//          per-slot rotation recurrence (cos/sin(o*phi) from (c1,s1)).
__global__ __launch_bounds__(256, 2) void spectral_one(
    const float* __restrict__ v,
    const float* __restrict__ w_real,
    const float* __restrict__ w_imag,
    float* __restrict__ out)
{
    const int blk = blockIdx.x;
    const int bt  = blk >> 2;        // 0..159
    const int hq  = blk & 3;         // h-quarter: global h = hq*64 + local
    const int t   = bt % T_;

    __shared__ float s_cs[64][36];   // [h_l][0..15]=C[o], [16..31]=S[o], +4 pad

    // ---------------- Phase 1: complex contraction ----------------
    {
        const int og  = threadIdx.x & 3;    // o-group (4 o's each)
        const int h_l = threadIdx.x >> 2;   // 0..63
        const int h_g = hq * 64 + h_l;

        float rr[MI_], ii[MI_];
        const float4* vp = reinterpret_cast<const float4*>(
            v + (size_t)(bt * D_ + h_g) * (2 * MI_));
        #pragma unroll
        for (int j = 0; j < MI_ / 4; ++j) {
            float4 q = vp[j];
            rr[4*j+0]=q.x; rr[4*j+1]=q.y; rr[4*j+2]=q.z; rr[4*j+3]=q.w;
        }
        #pragma unroll
        for (int j = 0; j < MI_ / 4; ++j) {
            float4 q = vp[MI_/4 + j];
            ii[4*j+0]=q.x; ii[4*j+1]=q.y; ii[4*j+2]=q.z; ii[4*j+3]=q.w;
        }

        const float* wrt = w_real + (size_t)t * MO_ * MI_;
        const float* wit = w_imag + (size_t)t * MO_ * MI_;

        float cq[4], sq[4];
        #pragma unroll
        for (int ol = 0; ol < 4; ++ol) {
            const int o = og * 4 + ol;
            const float4* wa = reinterpret_cast<const float4*>(wrt + o * MI_);
            const float4* wb = reinterpret_cast<const float4*>(wit + o * MI_);
            float c = 0.f, s = 0.f;
            #pragma unroll
            for (int mq = 0; mq < MI_ / 4; ++mq) {
                float4 a4 = wa[mq];
                float4 b4 = wb[mq];
                c = fmaf(rr[4*mq+0], a4.x, c); c = fmaf(-ii[4*mq+0], b4.x, c);
                s = fmaf(rr[4*mq+0], b4.x, s); s = fmaf( ii[4*mq+0], a4.x, s);
                c = fmaf(rr[4*mq+1], a4.y, c); c = fmaf(-ii[4*mq+1], b4.y, c);
                s = fmaf(rr[4*mq+1], b4.y, s); s = fmaf( ii[4*mq+1], a4.y, s);
                c = fmaf(rr[4*mq+2], a4.z, c); c = fmaf(-ii[4*mq+2], b4.z, c);
                s = fmaf(rr[4*mq+2], b4.z, s); s = fmaf( ii[4*mq+2], a4.z, s);
                c = fmaf(rr[4*mq+3], a4.w, c); c = fmaf(-ii[4*mq+3], b4.w, c);
                s = fmaf(rr[4*mq+3], b4.w, s); s = fmaf( ii[4*mq+3], a4.w, s);
            }
            cq[ol] = c; sq[ol] = s;
        }
        float4 cv; cv.x = cq[0]; cv.y = cq[1]; cv.z = cq[2]; cv.w = cq[3];
        float4 sv; sv.x = sq[0]; sv.y = sq[1]; sv.z = sq[2]; sv.w = sq[3];
        *reinterpret_cast<float4*>(&s_cs[h_l][og * 4])       = cv;
        *reinterpret_cast<float4*>(&s_cs[h_l][16 + og * 4])  = sv;
    }
    __syncthreads();

    // ---------------- Phase 2: mirror IFT ----------------
    {
        const int hp = threadIdx.x >> 4;    // 0..15 -> 4 h each
        const int ss = threadIdx.x & 15;    // slot set
        const int h2 = hp * 4;              // local h base

        // C,S for 4 h into registers (broadcast ds_read_b128, 2-way max)
        float Creg[4][16], Sreg[4][16];
        #pragma unroll
        for (int j = 0; j < 4; ++j) {
            const float4* row = reinterpret_cast<const float4*>(&s_cs[h2 + j][0]);
            #pragma unroll
            for (int q = 0; q < 4; ++q) {
                float4 c4 = row[q];
                float4 s4 = row[q + 4];
                Creg[j][4*q+0]=c4.x; Creg[j][4*q+1]=c4.y;
                Creg[j][4*q+2]=c4.z; Creg[j][4*q+3]=c4.w;
                Sreg[j][4*q+0]=s4.x; Sreg[j][4*q+1]=s4.y;
                Sreg[j][4*q+2]=s4.z; Sreg[j][4*q+3]=s4.w;
            }
        }

        float* obase = out + (size_t)bt * RES_ * D_ + hq * 64 + h2;

        // slots s = ss + 16k, k=0..6; s<=100 (101 mirror slots)
        #pragma unroll
        for (int k = 0; k < 7; ++k) {
            const int s = ss + 16 * k;
            if (s <= 100) {
                const float phi = (float)s * (TWO_PI / (float)RES_);
                float s1, c1;
                __sincosf(phi, &s1, &c1);

                float a0=0.f,a1=0.f,a2=0.f,a3=0.f;
                float b0=0.f,b1=0.f,b2=0.f,b3=0.f;
                float co = 1.f, so = 0.f;
                #pragma unroll
                for (int o = 0; o < MO_; ++o) {
                    a0 = fmaf(Creg[0][o], co, a0);
                    a1 = fmaf(Creg[1][o], co, a1);
                    a2 = fmaf(Creg[2][o], co, a2);
                    a3 = fmaf(Creg[3][o], co, a3);
                    b0 = fmaf(Sreg[0][o], so, b0);
                    b1 = fmaf(Sreg[1][o], so, b1);
                    b2 = fmaf(Sreg[2][o], so, b2);
                    b3 = fmaf(Sreg[3][o], so, b3);
                    const float nc = fmaf(co, c1, -(so * s1));
                    const float ns = fmaf(so, c1,  (co * s1));
                    co = nc; so = ns;
                }

                const int m = (s == 0) ? 0 : (RES_ - s);
                float4 lo, hi;
                lo.x = a0 - b0; hi.x = a0 + b0;
                lo.y = a1 - b1; hi.y = a1 + b1;
                lo.z = a2 - b2; hi.z = a2 + b2;
                lo.w = a3 - b3; hi.w = a3 + b3;
                *reinterpret_cast<float4*>(&obase[(size_t)s * D_]) = lo;
                *reinterpret_cast<float4*>(&obase[(size_t)m * D_]) = hi;
            }
        }
    }
}

extern "C" void kernel_launch(void* const* d_in, const int* in_sizes, int n_in,
                              void* d_out, int out_size, void* d_ws, size_t ws_size,
                              hipStream_t stream) {
    const float* v  = (const float*)d_in[0];
    const float* wr = (const float*)d_in[1];
    const float* wi = (const float*)d_in[2];
    float* out = (float*)d_out;
    spectral_one<<<B_ * T_ * 4, 256, 0, stream>>>(v, wr, wi, out);
}

// Round 6
// 31.886 us; speedup vs baseline: 1.1871x; 1.0891x over previous
//
#include <hip/hip_runtime.h>

#define B_   16
#define T_   10
#define D_   256
#define MI_  32
#define MO_  16
#define RES_ 200
#define TWO_PI 6.28318530717958647692f

#define HSLICE 32                 // h per block
#define NHS    (D_ / HSLICE)      // 8 h-slices
#define VPAD   68                 // padded row stride for s_v (64 + 4)
#define CSPAD  36                 // padded row stride for s_cs (32 + 4)

using f32x2 = __attribute__((ext_vector_type(2))) float;

// grid 1280 = bt(160) x hs(8); block 256.
// Phase 0: cooperative 8KB v-slice load (read v exactly once).
// Phase 1: thread=(h_l 32 x og 8): C,S for 2 o's each -> LDS.
// Phase 2: thread=(hp 16, 2h each x ss 16): mirror IFT, trig via rotation.
__global__ __launch_bounds__(256) void spectral_one(
    const float* __restrict__ v,
    const float* __restrict__ w_real,
    const float* __restrict__ w_imag,
    float* __restrict__ out)
{
    const int blk = blockIdx.x;          // 0..1279
    const int bt  = blk >> 3;
    const int hs  = blk & 7;
    const int t   = bt % T_;

    __shared__ float s_v[HSLICE * VPAD];     // 8.5 KB
    __shared__ float s_cs[HSLICE * CSPAD];   // 4.5 KB  [h][0..15]=C, [16..31]=S

    // ---------------- Phase 0: stage v slice (contiguous 8 KB) -------------
    {
        const float4* gv = reinterpret_cast<const float4*>(
            v + ((size_t)bt * D_ + hs * HSLICE) * (2 * MI_));
        #pragma unroll
        for (int j = 0; j < 2; ++j) {
            const int f = threadIdx.x + 256 * j;   // float4 index 0..511
            const int h = f >> 4;                  // 16 float4 per h-row
            const int m = (f & 15) * 4;
            *reinterpret_cast<float4*>(&s_v[h * VPAD + m]) = gv[f];
        }
    }
    __syncthreads();

    // ---------------- Phase 1: contraction ---------------------------------
    {
        const int h_l = threadIdx.x >> 3;    // 0..31
        const int og  = threadIdx.x & 7;     // o-pair group
        const int o0  = og * 2;

        float rr[MI_], ii[MI_];
        #pragma unroll
        for (int j = 0; j < 8; ++j) {
            float4 q = *reinterpret_cast<const float4*>(&s_v[h_l * VPAD + 4 * j]);
            rr[4*j+0]=q.x; rr[4*j+1]=q.y; rr[4*j+2]=q.z; rr[4*j+3]=q.w;
        }
        #pragma unroll
        for (int j = 0; j < 8; ++j) {
            float4 q = *reinterpret_cast<const float4*>(&s_v[h_l * VPAD + 32 + 4 * j]);
            ii[4*j+0]=q.x; ii[4*j+1]=q.y; ii[4*j+2]=q.z; ii[4*j+3]=q.w;
        }

        const float* wrt = w_real + ((size_t)t * MO_ + o0) * MI_;
        const float* wit = w_imag + ((size_t)t * MO_ + o0) * MI_;

        float cc[2], ssv[2];
        #pragma unroll
        for (int ol = 0; ol < 2; ++ol) {
            const float4* wa = reinterpret_cast<const float4*>(wrt + ol * MI_);
            const float4* wb = reinterpret_cast<const float4*>(wit + ol * MI_);
            float c = 0.f, s = 0.f;
            #pragma unroll
            for (int mq = 0; mq < 8; ++mq) {
                float4 a4 = wa[mq];
                float4 b4 = wb[mq];
                c = fmaf(rr[4*mq+0], a4.x, c); c = fmaf(-ii[4*mq+0], b4.x, c);
                s = fmaf(rr[4*mq+0], b4.x, s); s = fmaf( ii[4*mq+0], a4.x, s);
                c = fmaf(rr[4*mq+1], a4.y, c); c = fmaf(-ii[4*mq+1], b4.y, c);
                s = fmaf(rr[4*mq+1], b4.y, s); s = fmaf( ii[4*mq+1], a4.y, s);
                c = fmaf(rr[4*mq+2], a4.z, c); c = fmaf(-ii[4*mq+2], b4.z, c);
                s = fmaf(rr[4*mq+2], b4.z, s); s = fmaf( ii[4*mq+2], a4.z, s);
                c = fmaf(rr[4*mq+3], a4.w, c); c = fmaf(-ii[4*mq+3], b4.w, c);
                s = fmaf(rr[4*mq+3], b4.w, s); s = fmaf( ii[4*mq+3], a4.w, s);
            }
            cc[ol] = c; ssv[ol] = s;
        }
        float2 cw; cw.x = cc[0]; cw.y = cc[1];
        float2 sw; sw.x = ssv[0]; sw.y = ssv[1];
        *reinterpret_cast<float2*>(&s_cs[h_l * CSPAD + o0])       = cw;
        *reinterpret_cast<float2*>(&s_cs[h_l * CSPAD + 16 + o0])  = sw;
    }
    __syncthreads();

    // ---------------- Phase 2: mirror IFT ----------------------------------
    {
        const int hp = threadIdx.x >> 4;     // 0..15, 2 h each
        const int ss = threadIdx.x & 15;     // slot set
        const int h2 = hp * 2;

        float C0[MO_], C1[MO_], S0[MO_], S1[MO_];
        #pragma unroll
        for (int q = 0; q < 4; ++q) {
            float4 c0 = *reinterpret_cast<const float4*>(&s_cs[h2 * CSPAD + 4*q]);
            float4 s0 = *reinterpret_cast<const float4*>(&s_cs[h2 * CSPAD + 16 + 4*q]);
            float4 c1 = *reinterpret_cast<const float4*>(&s_cs[(h2+1) * CSPAD + 4*q]);
            float4 s1 = *reinterpret_cast<const float4*>(&s_cs[(h2+1) * CSPAD + 16 + 4*q]);
            C0[4*q+0]=c0.x; C0[4*q+1]=c0.y; C0[4*q+2]=c0.z; C0[4*q+3]=c0.w;
            S0[4*q+0]=s0.x; S0[4*q+1]=s0.y; S0[4*q+2]=s0.z; S0[4*q+3]=s0.w;
            C1[4*q+0]=c1.x; C1[4*q+1]=c1.y; C1[4*q+2]=c1.z; C1[4*q+3]=c1.w;
            S1[4*q+0]=s1.x; S1[4*q+1]=s1.y; S1[4*q+2]=s1.z; S1[4*q+3]=s1.w;
        }

        float* obase = out + (size_t)bt * RES_ * D_ + hs * HSLICE + h2;

        #pragma unroll
        for (int k = 0; k < 7; ++k) {
            const int sl = ss + 16 * k;
            if (sl <= 100) {
                const float phi = (float)sl * (TWO_PI / (float)RES_);
                float sn, cn;
                __sincosf(phi, &sn, &cn);

                float a0=0.f, a1=0.f, b0=0.f, b1=0.f;
                float co = 1.f, so = 0.f;
                #pragma unroll
                for (int o = 0; o < MO_; ++o) {
                    a0 = fmaf(C0[o], co, a0);
                    a1 = fmaf(C1[o], co, a1);
                    b0 = fmaf(S0[o], so, b0);
                    b1 = fmaf(S1[o], so, b1);
                    const float nc = fmaf(co, cn, -(so * sn));
                    const float ns = fmaf(so, cn,  (co * sn));
                    co = nc; so = ns;
                }

                const int mr = (sl == 0) ? 0 : (RES_ - sl);   // mirror row
                f32x2 lo, hi;
                lo.x = a0 - b0; lo.y = a1 - b1;
                hi.x = a0 + b0; hi.y = a1 + b1;
                __builtin_nontemporal_store(
                    lo, reinterpret_cast<f32x2*>(&obase[(size_t)sl * D_]));
                __builtin_nontemporal_store(
                    hi, reinterpret_cast<f32x2*>(&obase[(size_t)mr * D_]));
            }
        }
    }
}

extern "C" void kernel_launch(void* const* d_in, const int* in_sizes, int n_in,
                              void* d_out, int out_size, void* d_ws, size_t ws_size,
                              hipStream_t stream) {
    const float* v  = (const float*)d_in[0];
    const float* wr = (const float*)d_in[1];
    const float* wi = (const float*)d_in[2];
    float* out = (float*)d_out;
    spectral_one<<<B_ * T_ * NHS, 256, 0, stream>>>(v, wr, wi, out);
}

// Round 7
// 24.791 us; speedup vs baseline: 1.5269x; 1.2862x over previous
//
#include <hip/hip_runtime.h>

#define B_   16
#define T_   10
#define D_   256
#define MI_  32
#define MO_  16
#define RES_ 200
#define TWO_PI 6.28318530717958647692f

#define HSLICE 32
#define NHS    (D_ / HSLICE)              // 8
#define VPAD   68
#define BT_STRIDE (2 * MO_ * D_)          // 8192 floats: [C planes][S planes]
#define CS_BYTES ((size_t)B_ * T_ * BT_STRIDE * sizeof(float))   // 5.24 MB

using f32x4 = __attribute__((ext_vector_type(4))) float;

// ---------- Kernel A: contraction -> ws transposed [bt][{C,S}][o][h] -------
// grid 1280 = bt(160) x hs(8); block 256 = og(8) x h_l(32).
__global__ __launch_bounds__(256) void spectral_cs(
    const float* __restrict__ v,
    const float* __restrict__ w_real,
    const float* __restrict__ w_imag,
    float* __restrict__ ws)
{
    const int blk = blockIdx.x;
    const int bt  = blk >> 3;
    const int hs  = blk & 7;
    const int t   = bt % T_;

    __shared__ float s_v[HSLICE * VPAD];     // 8.5 KB

    // cooperative v-slice stage (v read exactly once per element)
    {
        const float4* gv = reinterpret_cast<const float4*>(
            v + ((size_t)bt * D_ + hs * HSLICE) * (2 * MI_));
        #pragma unroll
        for (int j = 0; j < 2; ++j) {
            const int f = threadIdx.x + 256 * j;
            const int h = f >> 4;
            const int m = (f & 15) * 4;
            *reinterpret_cast<float4*>(&s_v[h * VPAD + m]) = gv[f];
        }
    }
    __syncthreads();

    // lanes 0..31 = h (contiguous 128B store runs), tid>>5 = o-pair group
    const int og  = threadIdx.x >> 5;
    const int h_l = threadIdx.x & 31;
    const int o0  = og * 2;
    const int h_g = hs * HSLICE + h_l;

    float rr[MI_], ii[MI_];
    #pragma unroll
    for (int j = 0; j < 8; ++j) {
        float4 q = *reinterpret_cast<const float4*>(&s_v[h_l * VPAD + 4 * j]);
        rr[4*j+0]=q.x; rr[4*j+1]=q.y; rr[4*j+2]=q.z; rr[4*j+3]=q.w;
    }
    #pragma unroll
    for (int j = 0; j < 8; ++j) {
        float4 q = *reinterpret_cast<const float4*>(&s_v[h_l * VPAD + 32 + 4 * j]);
        ii[4*j+0]=q.x; ii[4*j+1]=q.y; ii[4*j+2]=q.z; ii[4*j+3]=q.w;
    }

    const float* wrt = w_real + ((size_t)t * MO_ + o0) * MI_;
    const float* wit = w_imag + ((size_t)t * MO_ + o0) * MI_;

    float* wsb = ws + (size_t)bt * BT_STRIDE;
    #pragma unroll
    for (int ol = 0; ol < 2; ++ol) {
        const float4* wa = reinterpret_cast<const float4*>(wrt + ol * MI_);
        const float4* wb = reinterpret_cast<const float4*>(wit + ol * MI_);
        float c = 0.f, s = 0.f;
        #pragma unroll
        for (int mq = 0; mq < 8; ++mq) {
            float4 a4 = wa[mq];
            float4 b4 = wb[mq];
            c = fmaf(rr[4*mq+0], a4.x, c); c = fmaf(-ii[4*mq+0], b4.x, c);
            s = fmaf(rr[4*mq+0], b4.x, s); s = fmaf( ii[4*mq+0], a4.x, s);
            c = fmaf(rr[4*mq+1], a4.y, c); c = fmaf(-ii[4*mq+1], b4.y, c);
            s = fmaf(rr[4*mq+1], b4.y, s); s = fmaf( ii[4*mq+1], a4.y, s);
            c = fmaf(rr[4*mq+2], a4.z, c); c = fmaf(-ii[4*mq+2], b4.z, c);
            s = fmaf(rr[4*mq+2], b4.z, s); s = fmaf( ii[4*mq+2], a4.z, s);
            c = fmaf(rr[4*mq+3], a4.w, c); c = fmaf(-ii[4*mq+3], b4.w, c);
            s = fmaf(rr[4*mq+3], b4.w, s); s = fmaf( ii[4*mq+3], a4.w, s);
        }
        const int o = o0 + ol;
        wsb[o * D_ + h_g]              = c;   // C plane, 32 lanes = 128B run
        wsb[MO_ * D_ + o * D_ + h_g]   = s;   // S plane
    }
}

// ---------- Kernel B: row-wave IFT — 1KB contiguous wave stores ------------
// grid 640 = bt(160) x qb(4); block 256 = 4 waves; wave = full output row.
// lane owns h = 4*lane..4*lane+3; C,S held in 128 VGPRs; trig by rotation.
__global__ __launch_bounds__(256) void spectral_ift(
    const float* __restrict__ ws,
    float* __restrict__ out)
{
    const int blk  = blockIdx.x;
    const int bt   = blk >> 2;
    const int qb   = blk & 3;
    const int wave = threadIdx.x >> 6;
    const int lane = threadIdx.x & 63;
    const int g    = qb * 4 + wave;      // 0..15: wave index within bt
    const int h0   = lane * 4;

    const float* wsb = ws + (size_t)bt * BT_STRIDE;
    float C[MO_][4], S[MO_][4];
    #pragma unroll
    for (int o = 0; o < MO_; ++o) {
        float4 c4 = *reinterpret_cast<const float4*>(&wsb[o * D_ + h0]);
        float4 s4 = *reinterpret_cast<const float4*>(&wsb[MO_ * D_ + o * D_ + h0]);
        C[o][0]=c4.x; C[o][1]=c4.y; C[o][2]=c4.z; C[o][3]=c4.w;
        S[o][0]=s4.x; S[o][1]=s4.y; S[o][2]=s4.z; S[o][3]=s4.w;
    }

    float* ob = out + (size_t)bt * RES_ * D_;

    #pragma unroll
    for (int k = 0; k < 7; ++k) {
        const int s = g + 16 * k;        // wave-uniform slot
        if (s <= 100) {
            const float phi = (float)s * (TWO_PI / (float)RES_);
            float s1, c1;
            __sincosf(phi, &s1, &c1);

            float a0=0.f,a1=0.f,a2=0.f,a3=0.f;
            float b0=0.f,b1=0.f,b2=0.f,b3=0.f;
            float co = 1.f, so = 0.f;
            #pragma unroll
            for (int o = 0; o < MO_; ++o) {
                a0 = fmaf(C[o][0], co, a0);
                a1 = fmaf(C[o][1], co, a1);
                a2 = fmaf(C[o][2], co, a2);
                a3 = fmaf(C[o][3], co, a3);
                b0 = fmaf(S[o][0], so, b0);
                b1 = fmaf(S[o][1], so, b1);
                b2 = fmaf(S[o][2], so, b2);
                b3 = fmaf(S[o][3], so, b3);
                const float nc = fmaf(co, c1, -(so * s1));
                const float ns = fmaf(so, c1,  (co * s1));
                co = nc; so = ns;
            }

            const int mr = (s == 0) ? 0 : (RES_ - s);
            f32x4 lo, hi;
            lo.x = a0 - b0; lo.y = a1 - b1; lo.z = a2 - b2; lo.w = a3 - b3;
            hi.x = a0 + b0; hi.y = a1 + b1; hi.z = a2 + b2; hi.w = a3 + b3;
            // full-row wave store: 64 lanes x 16B = 1KB contiguous
            __builtin_nontemporal_store(
                lo, reinterpret_cast<f32x4*>(&ob[(size_t)s  * D_ + h0]));
            __builtin_nontemporal_store(
                hi, reinterpret_cast<f32x4*>(&ob[(size_t)mr * D_ + h0]));
        }
    }
}

extern "C" void kernel_launch(void* const* d_in, const int* in_sizes, int n_in,
                              void* d_out, int out_size, void* d_ws, size_t ws_size,
                              hipStream_t stream) {
    const float* v  = (const float*)d_in[0];
    const float* wr = (const float*)d_in[1];
    const float* wi = (const float*)d_in[2];
    float* out = (float*)d_out;
    float* ws  = (float*)d_ws;

    spectral_cs <<<B_ * T_ * NHS, 256, 0, stream>>>(v, wr, wi, ws);
    spectral_ift<<<B_ * T_ * 4,   256, 0, stream>>>(ws, out);
}